// Round 19
// baseline (112.575 us; speedup 1.0000x reference)
//
#include <hip/hip_runtime.h>
#include <math.h>

#define NPTS 4096
#define NEPS 4.096e-4f                 // 4096 * 1e-7
#define E2   7.3890560989306495f       // exp(2)
#define E2M1 6.3890560989306495f       // exp(2) - 1

typedef float  f32x4 __attribute__((ext_vector_type(4)));
typedef short  s16x8 __attribute__((ext_vector_type(8)));

static __device__ __forceinline__ unsigned short f2b(float x) {
    unsigned u = __builtin_bit_cast(unsigned, x);
    return (unsigned short)((u + 0x7fffu + ((u >> 16) & 1u)) >> 16);
}
static __device__ __forceinline__ float b2f(unsigned short h) {
    return __builtin_bit_cast(float, (unsigned)h << 16);
}

// fragment-order (swizzled) element offset for element (r,c) of an R-row matrix
static __device__ __forceinline__ size_t swz(int r, int c, int R16) {
    return (((size_t)((c >> 5) * R16 + (r >> 4))) << 9)
         + ((size_t)((r & 15) + (((c & 31) >> 3) << 4)) << 3) + (c & 7);
}

// ---------------------------------------------------------------------------
// prep (3553 blocks) — unchanged from R18
// ---------------------------------------------------------------------------
__global__ __launch_bounds__(256) void prep_kernel(
    const float* __restrict__ roi_feat, const float* __restrict__ W_roi_feat,
    const float* __restrict__ roi_cls_W1,
    const float* __restrict__ rpn_feat, const float* __restrict__ W_rpn_feat,
    const float* __restrict__ rpn_cls_W1, const float* __restrict__ rpn_bbox_W1,
    const float* __restrict__ rpn_cls_b1, const float* __restrict__ rpn_bbox_b1,
    const float* __restrict__ roi_del, const float* __restrict__ rpn_del,
    const float* __restrict__ W_roi_del, const float* __restrict__ W_roi_sc,
    const float* __restrict__ b_roi_feat, const float* __restrict__ b_roi_del,
    const float* __restrict__ b_roi_sc,  const float* __restrict__ roi_cls_b1v,
    const float* __restrict__ W_rpn_del, const float* __restrict__ W_rpn_sc,
    const float* __restrict__ b_rpn_feat, const float* __restrict__ b_rpn_del,
    const float* __restrict__ b_rpn_sc,
    unsigned short* __restrict__ roi_feat_sw,
    unsigned short* __restrict__ WfT_roi_c, unsigned short* __restrict__ WfT_roi_b,
    unsigned short* __restrict__ roi_W1_sw,
    unsigned short* __restrict__ rpn_feat_sw,
    unsigned short* __restrict__ WfT_rpn_c, unsigned short* __restrict__ WfT_rpn_b,
    unsigned short* __restrict__ rpn_cW1_sw, unsigned short* __restrict__ rpn_bW1_sw,
    unsigned short* __restrict__ Db_roi, unsigned short* __restrict__ Db_rpn,
    float* __restrict__ ext, float* __restrict__ zerobuf,
    float* __restrict__ out)
{
    const int b = blockIdx.x, t = threadIdx.x;
    if (b < 2688) {
        const float* in; unsigned short* o; int base, cshift, R16;
        if      (b < 2048) { in = roi_feat;   o = roi_feat_sw; base = b;        cshift = 10; R16 = 256; }
        else if (b < 2176) { in = roi_cls_W1; o = roi_W1_sw;   base = b - 2048; cshift = 10; R16 = 16;  }
        else               { in = rpn_feat;   o = rpn_feat_sw; base = b - 2176; cshift = 8;  R16 = 256; }
        const int i = base * 2048 + t * 8;
        const int r = i >> cshift, c = i & ((1 << cshift) - 1);
        const float4 v0 = *(const float4*)&in[i];
        const float4 v1 = *(const float4*)&in[i + 4];
        s16x8 pk;
        pk[0] = (short)f2b(v0.x); pk[1] = (short)f2b(v0.y);
        pk[2] = (short)f2b(v0.z); pk[3] = (short)f2b(v0.w);
        pk[4] = (short)f2b(v1.x); pk[5] = (short)f2b(v1.y);
        pk[6] = (short)f2b(v1.z); pk[7] = (short)f2b(v1.w);
        *(s16x8*)(o + swz(r, c, R16)) = pk;
    } else if (b < 2720) {
        const bool cls = b < 2704;
        const float* W = cls ? rpn_cls_W1 : rpn_bbox_W1;
        unsigned short* o = cls ? rpn_cW1_sw : rpn_bW1_sw;
        const int local = b - (cls ? 2688 : 2704);
        const int i = local * 2048 + t * 8;
        const int r = i >> 8, c = i & 255;
        s16x8 pk;
#pragma unroll
        for (int u = 0; u < 8; ++u)
            pk[u] = (r < 64) ? (short)f2b(W[r * 256 + c + u]) : (short)0;
        *(s16x8*)(o + swz(r, c, 8)) = pk;
    } else if (b < 2752) {
        const int row = (b - 2720) * 256 + t;
        const int mat = row >> 12, r = row & 4095;
        const float* D = mat ? rpn_del : roi_del;
        unsigned short* o = mat ? Db_rpn : Db_roi;
        const float4 dv = *(const float4*)&D[(size_t)r * 4];
        ushort4 d4; d4.x = f2b(dv.x); d4.y = f2b(dv.y); d4.z = f2b(dv.z); d4.w = f2b(dv.w);
        unsigned short* p = o + (size_t)r * 32;
        ushort4 z4 = {0, 0, 0, 0};
        *(ushort4*)p = d4;
        *(ushort4*)(p + 4)  = z4;
        *(ushort4*)(p + 8)  = z4; *(ushort4*)(p + 12) = z4;
        *(ushort4*)(p + 16) = z4; *(ushort4*)(p + 20) = z4;
        *(ushort4*)(p + 24) = z4; *(ushort4*)(p + 28) = z4;
    } else if (b < 3008) {
        const int e = b - 2752;
        const int job = e >> 6;
        const int w = t >> 6, l = t & 63;
        const int hl = (e & 63) * 4 + w;
        const float *W1, *Wd, *Wsc, *bA, *bB, *bC, *b1;
        int K, ooff, Hact, Htot;
        if (job == 0)      { W1 = roi_cls_W1;  K = 1024; ooff = 0;    Wd = W_roi_del; Wsc = W_roi_sc; bA = b_roi_feat; bB = b_roi_del; bC = b_roi_sc; b1 = roi_cls_b1v; Hact = 256; Htot = 256; }
        else if (job == 1) { W1 = roi_cls_W1;  K = 1024; ooff = 1024; Wd = W_roi_del; Wsc = W_roi_sc; bA = b_roi_feat; bB = b_roi_del; bC = b_roi_sc; b1 = roi_cls_b1v; Hact = 256; Htot = 256; }
        else if (job == 2) { W1 = rpn_cls_W1;  K = 256;  ooff = 0;    Wd = W_rpn_del; Wsc = W_rpn_sc; bA = b_rpn_feat; bB = b_rpn_del; bC = b_rpn_sc; b1 = rpn_cls_b1;  Hact = 64;  Htot = 128; }
        else               { W1 = rpn_bbox_W1; K = 256;  ooff = 256;  Wd = W_rpn_del; Wsc = W_rpn_sc; bA = b_rpn_feat; bB = b_rpn_del; bC = b_rpn_sc; b1 = rpn_bbox_b1; Hact = 64;  Htot = 128; }
        if (hl >= Htot) return;
        float a0 = 0.f, a1 = 0.f, a2 = 0.f, a3 = 0.f, a4 = 0.f, a5 = 0.f;
        if (hl < Hact) {
            for (int o = l; o < K; o += 64) {
                const float wv = W1[hl * K + o];
                const float4 wd = *(const float4*)&Wd[(ooff + o) * 4];
                a0 = fmaf(wv, wd.x, a0); a1 = fmaf(wv, wd.y, a1);
                a2 = fmaf(wv, wd.z, a2); a3 = fmaf(wv, wd.w, a3);
                a4 = fmaf(wv, Wsc[ooff + o], a4);
                a5 = fmaf(wv, bA[ooff + o] + bB[ooff + o] + bC[ooff + o], a5);
            }
            for (int off = 32; off; off >>= 1) {
                a0 += __shfl_xor(a0, off, 64); a1 += __shfl_xor(a1, off, 64);
                a2 += __shfl_xor(a2, off, 64); a3 += __shfl_xor(a3, off, 64);
                a4 += __shfl_xor(a4, off, 64); a5 += __shfl_xor(a5, off, 64);
            }
        }
        if (l == 0) {
            float* ej = ext + job * 1536;
            ej[hl * 4 + 0] = a0; ej[hl * 4 + 1] = a1;
            ej[hl * 4 + 2] = a2; ej[hl * 4 + 3] = a3;
            ej[1024 + hl] = a4;
            ej[1280 + hl] = (hl < Hact) ? (a5 + b1[hl]) : 0.f;
        }
    } else if (b < 3552) {
        __shared__ __align__(16) unsigned short ldsT[64][72];
        const float* src; unsigned short* dst;
        int ld, R16, o0g, o_loc0, c0;
        if (b < 3520) {
            const int tt = b - 3008;
            const int half = tt >> 8, tile = tt & 255;
            const int ot = tile & 15, ct = tile >> 4;
            src = W_roi_feat; ld = 1024; R16 = 64;
            o0g = half * 1024 + ot * 64; o_loc0 = ot * 64; c0 = ct * 64;
            dst = half ? WfT_roi_b : WfT_roi_c;
        } else {
            const int tt = b - 3520;
            const int half = tt >> 4, tile = tt & 15;
            const int ot = tile & 3, ct = tile >> 2;
            src = W_rpn_feat; ld = 256; R16 = 16;
            o0g = half * 256 + ot * 64; o_loc0 = ot * 64; c0 = ct * 64;
            dst = half ? WfT_rpn_b : WfT_rpn_c;
        }
        const int r = t >> 2, cg = (t & 3) << 4;
        const float* sp = src + (size_t)(o0g + r) * ld + c0 + cg;
        const float4 v0 = *(const float4*)(sp + 0);
        const float4 v1 = *(const float4*)(sp + 4);
        const float4 v2 = *(const float4*)(sp + 8);
        const float4 v3 = *(const float4*)(sp + 12);
        const float vv[16] = {v0.x,v0.y,v0.z,v0.w, v1.x,v1.y,v1.z,v1.w,
                              v2.x,v2.y,v2.z,v2.w, v3.x,v3.y,v3.z,v3.w};
#pragma unroll
        for (int k = 0; k < 16; ++k)
            ldsT[cg + k][r] = f2b(vv[k]);
        __syncthreads();
#pragma unroll
        for (int qq = 0; qq < 2; ++qq) {
            const int q = t + qq * 256;
            const int s = q >> 6, l = q & 63;
            const int kj = s & 1, si = s >> 1;
            const int cl = si * 16 + (l & 15);
            const int ol = kj * 32 + ((l >> 4) << 3);
            const s16x8 val = *(const s16x8*)&ldsT[cl][ol];
            const size_t base = ((size_t)(((o_loc0 >> 5) + kj) * R16 + (c0 >> 4) + si)) << 9;
            *(s16x8*)(dst + base + l * 8) = val;
        }
    } else {
        *(float4*)&zerobuf[t * 4] = float4{0.f, 0.f, 0.f, 0.f};
        if (t < 4) out[184 + t] = 0.f;
    }
}

// ---------------------------------------------------------------------------
// Register-direct MFMA GEMM, WAVE-PER-BLOCK (64 thr, one 64x64 tile), depth-4.
// ---------------------------------------------------------------------------
struct GemmJob {
    const unsigned short *A, *W;
    unsigned short *C;
    const float *bias;
    const float *del, *Wd, *bd, *sc, *Wsc, *bs;
    int strideA, strideB;
    int M16;
    int ldc;
    int K, nbx, bstart;
};
struct GemmJobs { GemmJob j[4]; int n; };

#define LDSET(Av, Bv)                                          \
    {                                                          \
        _Pragma("unroll")                                      \
        for (int m = 0; m < 4; ++m) {                          \
            Av[m] = *(const s16x8*)(pa + (m << 9));            \
            Bv[m] = *(const s16x8*)(pb + (m << 9));            \
        }                                                      \
        pa += jb.strideA; pb += jb.strideB;                    \
    }

#define MMSET(Av, Bv)                                          \
    {                                                          \
        _Pragma("unroll")                                      \
        for (int m = 0; m < 4; ++m)                            \
            _Pragma("unroll")                                  \
            for (int n = 0; n < 4; ++n)                        \
                acc[m][n] = __builtin_amdgcn_mfma_f32_16x16x32_bf16( \
                    Av[m], Bv[n], acc[m][n], 0, 0, 0);         \
    }

template<bool EXTRAS, bool CSWZ, bool RELU>
__global__ __launch_bounds__(64) void gemm_reg(GemmJobs jobs)
{
    const int bid = blockIdx.x;
    int ji = 0;
#pragma unroll
    for (int i = 1; i < 4; ++i)
        if (i < jobs.n && bid >= jobs.j[i].bstart) ji = i;
    const GemmJob jb = jobs.j[ji];
    const int local = bid - jb.bstart;
    const int bx = local % jb.nbx, by = local / jb.nbx;

    const int l = threadIdx.x & 63;
    const int fr = l & 15, fq = l >> 4;

    const int sA0 = by * 4;
    const int sB0 = bx * 4;
    const unsigned short* pa = jb.A + ((size_t)sA0 << 9) + (size_t)(l * 8);
    const unsigned short* pb = jb.W + ((size_t)sB0 << 9) + (size_t)(l * 8);

    f32x4 acc[4][4] = {};
    s16x8 A0[4], B0[4], A1[4], B1[4], A2[4], B2[4], A3[4], B3[4];

    const int niter = jb.K >> 5;
    LDSET(A0, B0);
    LDSET(A1, B1);
    LDSET(A2, B2);

    for (int it = 0; it < niter; it += 4) {
        if (it + 3 < niter) LDSET(A3, B3);
        MMSET(A0, B0);
        if (it + 4 < niter) LDSET(A0, B0);
        MMSET(A1, B1);
        if (it + 5 < niter) LDSET(A1, B1);
        MMSET(A2, B2);
        if (it + 6 < niter) LDSET(A2, B2);
        MMSET(A3, B3);
    }

#pragma unroll
    for (int n = 0; n < 4; ++n) {
        const int cc = (sB0 + n) * 16 + fr;
        float cadd = jb.bias[cc];
        float wd0 = 0.f, wd1 = 0.f, wd2 = 0.f, wd3 = 0.f, wscv = 0.f;
        if (EXTRAS) {
            cadd += jb.bd[cc] + jb.bs[cc];
            const float4 w4 = *(const float4*)&jb.Wd[cc * 4];
            wd0 = w4.x; wd1 = w4.y; wd2 = w4.z; wd3 = w4.w;
            wscv = jb.Wsc[cc];
        }
#pragma unroll
        for (int m = 0; m < 4; ++m) {
            const int si = sA0 + m;
            unsigned short* cp;
            if (CSWZ) {
                const int kj = cc >> 5;
                cp = jb.C + (((size_t)(kj * jb.M16 + si)) << 9)
                   + (((size_t)((cc & 31) >> 3)) << 7) + (cc & 7);
            }
#pragma unroll
            for (int j = 0; j < 4; ++j) {
                const int rr = fq * 4 + j;
                const int row = si * 16 + rr;
                float v = acc[m][n][j] + cadd;
                if (EXTRAS) {
                    const float4 dm = *(const float4*)&jb.del[row * 4];
                    v += dm.x * wd0 + dm.y * wd1 + dm.z * wd2 + dm.w * wd3
                       + jb.sc[row] * wscv;
                }
                if (RELU) v = fmaxf(v, 0.f);
                if (CSWZ) cp[(size_t)rr << 3] = f2b(v);
                else      jb.C[(size_t)row * jb.ldc + cc] = f2b(v);
            }
        }
    }
}

// ---------------------------------------------------------------------------
// alphas for all 4 matrices (unchanged)
// ---------------------------------------------------------------------------
__global__ __launch_bounds__(256) void alphas_all(
    const unsigned short* __restrict__ h_rpn_c, const unsigned short* __restrict__ h_rpn_b,
    const unsigned short* __restrict__ h_roi_c, const unsigned short* __restrict__ h_roi_b,
    const float* __restrict__ W2_rc, const float* __restrict__ W2_rb,
    const float* __restrict__ W2_oc,
    const float* __restrict__ b2_rc, const float* __restrict__ b2_rb,
    const float* __restrict__ b2_oc,
    const int* __restrict__ iter_ptr,
    float* __restrict__ A_rpn_c, float* __restrict__ A_rpn_b,
    float* __restrict__ A_roi_c, float* __restrict__ A_roi_b,
    unsigned short* __restrict__ Ab_all)
{
    const int vrow = blockIdx.x * 4 + (threadIdx.x >> 6);
    const int mat = vrow >> 12, row = vrow & 4095;
    const unsigned short* H; const float *W2, *b2; float* Ao; int ldh, Hd;
    if (mat == 0)      { H = h_rpn_c; W2 = W2_rc; b2 = b2_rc; Ao = A_rpn_c; ldh = 128; Hd = 64; }
    else if (mat == 1) { H = h_rpn_b; W2 = W2_rb; b2 = b2_rb; Ao = A_rpn_b; ldh = 128; Hd = 64; }
    else if (mat == 2) { H = h_roi_c; W2 = W2_oc; b2 = b2_oc; Ao = A_roi_c; ldh = 256; Hd = 256; }
    else               { H = h_roi_b; W2 = W2_oc; b2 = b2_oc; Ao = A_roi_b; ldh = 256; Hd = 256; }

    const int l = threadIdx.x & 63;
    float acc[8] = {};
    for (int m = l * 4; m < Hd; m += 256) {
        const ushort4 h4 = *(const ushort4*)&H[(size_t)row * ldh + m];
        const float h0 = b2f(h4.x), h1 = b2f(h4.y), h2 = b2f(h4.z), h3 = b2f(h4.w);
#pragma unroll
        for (int o = 0; o < 8; ++o) {
            const float4 w4 = *(const float4*)&W2[o * Hd + m];
            acc[o] += h0 * w4.x + h1 * w4.y + h2 * w4.z + h3 * w4.w;
        }
    }
#pragma unroll
    for (int o = 0; o < 8; ++o)
        for (int off = 32; off; off >>= 1)
            acc[o] += __shfl_xor(acc[o], off, 64);

    const int it = *iter_ptr;
    const float temp = fmaxf(1.0f, 30.0f * (float)(90000 - it) / 90000.0f);
    float lg[8], mx = -1e30f;
#pragma unroll
    for (int o = 0; o < 8; ++o) { lg[o] = (acc[o] + b2[o]) / temp; mx = fmaxf(mx, lg[o]); }
    float s = 0.f;
#pragma unroll
    for (int o = 0; o < 8; ++o) { lg[o] = __expf(lg[o] - mx); s += lg[o]; }
    const float inv = 1.0f / s;
    if (l < 8) Ao[(size_t)row * 8 + l] = lg[l] * inv;
    unsigned short* Ab = Ab_all + (size_t)mat * 131072 + (size_t)row * 32;
    if (l == 0) {
        ushort4 o0, o1;
        o0.x = f2b(lg[0]*inv); o0.y = f2b(lg[1]*inv); o0.z = f2b(lg[2]*inv); o0.w = f2b(lg[3]*inv);
        o1.x = f2b(lg[4]*inv); o1.y = f2b(lg[5]*inv); o1.z = f2b(lg[6]*inv); o1.w = f2b(lg[7]*inv);
        *(ushort4*)Ab = o0; *(ushort4*)(Ab + 4) = o1;
    } else if (l < 4) {
        ushort4 z = {0,0,0,0};
        *(ushort4*)(Ab + l * 8)     = z;
        *(ushort4*)(Ab + l * 8 + 4) = z;
    }
}

// ---------------------------------------------------------------------------
// finale (2083 blocks):
//  b<2048: k-split loss pair-pass (batch-phased).
//          li=b>>9; local=b&511; jblk=local>>2 (32 j), ksplit=local&3 (1024 k)
//          part[(li*4096+j)*4 + ksplit][3] = (Sx, Sg, U)
//  2048..2050: column means; 2051..2082: class-sum partials (no atomics)
// ---------------------------------------------------------------------------
__global__ __launch_bounds__(256) void finale_kernel(
    const unsigned short* __restrict__ Ab_all,
    const unsigned short* __restrict__ Db_roi, const unsigned short* __restrict__ Db_rpn,
    const float* __restrict__ A_roi_c, const float* __restrict__ A_rpn_c,
    const float* __restrict__ A_roi_b, const float* __restrict__ A_rpn_b,
    const int* __restrict__ roi_class, const int* __restrict__ rpn_class,
    float* __restrict__ part, float* __restrict__ part2, float* __restrict__ out)
{
    const int b = blockIdx.x, t = threadIdx.x;
    const int w = t >> 6, l = t & 63;
    const int fr = l & 15, fq = l >> 4;

    if (b < 2048) {
        __shared__ float sh[4][2][16][3];
        const int li = b >> 9;
        const int local = b & 511;
        const int jblk = local >> 2, ksplit = local & 3;
        const int j0 = jblk * 32;
        const bool is_cls = li < 2;
        const int mat = (li == 0) ? 2 : (li == 1) ? 0 : (li == 2) ? 3 : 1;
        const unsigned short* Ab = Ab_all + (size_t)mat * 131072;
        const unsigned short* Db = (li == 2) ? Db_roi : Db_rpn;

        s16x8 bj[2], dj[2];
#pragma unroll
        for (int jt = 0; jt < 2; ++jt) {
            const int j = j0 + jt * 16;
            bj[jt] = *(const s16x8*)&Ab[(size_t)(j + fr) * 32 + fq * 8];
            if (!is_cls) dj[jt] = *(const s16x8*)&Db[(size_t)(j + fr) * 32 + fq * 8];
        }

        float Sx[2] = {}, Sg[2] = {}, U[2] = {};
        const int kbase0 = ksplit * 1024 + w * 256;
        const f32x4 zc = {0.f, 0.f, 0.f, 0.f};

        if (is_cls) {
            for (int ob = 0; ob < 2; ++ob) {           // 2 batches x 8 chunks x 16 k
                const int kb0 = kbase0 + ob * 128;
                s16x8 af[8];
#pragma unroll
                for (int u = 0; u < 8; ++u)
                    af[u] = *(const s16x8*)&Ab[(size_t)(kb0 + u * 16 + fr) * 32 + fq * 8];
                f32x4 g[8][2];
#pragma unroll
                for (int u = 0; u < 8; ++u)
#pragma unroll
                    for (int jt = 0; jt < 2; ++jt)
                        g[u][jt] = __builtin_amdgcn_mfma_f32_16x16x32_bf16(af[u], bj[jt], zc, 0, 0, 0);
#pragma unroll
                for (int u = 0; u < 8; ++u)
#pragma unroll
                    for (int jt = 0; jt < 2; ++jt)
#pragma unroll
                        for (int r = 0; r < 4; ++r)
                            Sx[jt] += __expf(2.f * g[u][jt][r]);
            }
        } else {
            for (int ob = 0; ob < 4; ++ob) {           // 4 batches x 4 chunks x 16 k
                const int kb0 = kbase0 + ob * 64;
                s16x8 af[4], df[4];
#pragma unroll
                for (int u = 0; u < 4; ++u) {
                    af[u] = *(const s16x8*)&Ab[(size_t)(kb0 + u * 16 + fr) * 32 + fq * 8];
                    df[u] = *(const s16x8*)&Db[(size_t)(kb0 + u * 16 + fr) * 32 + fq * 8];
                }
                f32x4 g[4][2], gd[4][2];
#pragma unroll
                for (int u = 0; u < 4; ++u)
#pragma unroll
                    for (int jt = 0; jt < 2; ++jt) {
                        g[u][jt]  = __builtin_amdgcn_mfma_f32_16x16x32_bf16(af[u], bj[jt], zc, 0, 0, 0);
                        gd[u][jt] = __builtin_amdgcn_mfma_f32_16x16x32_bf16(df[u], dj[jt], zc, 0, 0, 0);
                    }
#pragma unroll
                for (int u = 0; u < 4; ++u)
#pragma unroll
                    for (int jt = 0; jt < 2; ++jt)
#pragma unroll
                        for (int r = 0; r < 4; ++r) {
                            const float gv = g[u][jt][r];
                            const float ed = __expf(2.f * gd[u][jt][r]);
                            Sx[jt] += __expf(2.f * gv);
                            Sg[jt] += ed;
                            U[jt] = fmaf(ed, gv, U[jt]);
                        }
            }
        }

#pragma unroll
        for (int jt = 0; jt < 2; ++jt) {
            float vx = Sx[jt], vg = Sg[jt], vu = U[jt];
            for (int off = 16; off <= 32; off <<= 1) {
                vx += __shfl_xor(vx, off, 64);
                vg += __shfl_xor(vg, off, 64);
                vu += __shfl_xor(vu, off, 64);
            }
            if (fq == 0) {
                sh[w][jt][fr][0] = vx; sh[w][jt][fr][1] = vg; sh[w][jt][fr][2] = vu;
            }
        }
        __syncthreads();
        if (t < 32) {
            const int jt = t >> 4, jl = t & 15;
            float vx = 0.f, vg = 0.f, vu = 0.f;
#pragma unroll
            for (int wv = 0; wv < 4; ++wv) {
                vx += sh[wv][jt][jl][0]; vg += sh[wv][jt][jl][1]; vu += sh[wv][jt][jl][2];
            }
            const int j = j0 + jt * 16 + jl;
            float* p = part + (((size_t)li * 4096 + j) * 4 + ksplit) * 3;
            p[0] = vx; p[1] = vg; p[2] = vu;
        }
    } else if (b < 2051) {
        __shared__ float S4[4][8];
        const float* A = (b == 2048) ? A_rpn_c : (b == 2049) ? A_rpn_b : A_roi_b;
        const int off0 = (b == 2048) ? 0 : (b == 2049) ? 8 : 176;
        float acc[8] = {};
        for (int r = t; r < NPTS; r += 256) {
            const float4 v0 = *(const float4*)&A[(size_t)r * 8];
            const float4 v1 = *(const float4*)&A[(size_t)r * 8 + 4];
            acc[0]+=v0.x; acc[1]+=v0.y; acc[2]+=v0.z; acc[3]+=v0.w;
            acc[4]+=v1.x; acc[5]+=v1.y; acc[6]+=v1.z; acc[7]+=v1.w;
        }
#pragma unroll
        for (int o = 0; o < 8; ++o) {
            float v = acc[o];
            for (int offs = 32; offs; offs >>= 1) v += __shfl_xor(v, offs, 64);
            if (l == 0) S4[w][o] = v;
        }
        __syncthreads();
        if (t < 8) {
            const float s = S4[0][t] + S4[1][t] + S4[2][t] + S4[3][t];
            out[off0 + t] = s * (1.f / 4096.f);
        }
    } else {
        __shared__ float shs[4][20][8];
        __shared__ float shc[4][20];
        const int local = b - 2051;
        const int side = local >> 4, blk = local & 15;
        const float* A = side ? A_rpn_c : A_roi_c;
        const int* cls = side ? rpn_class : roi_class;
        const int row = blk * 256 + t;
        const float4 a0 = *(const float4*)&A[(size_t)row * 8];
        const float4 a1 = *(const float4*)&A[(size_t)row * 8 + 4];
        const int myc = cls[row];
#pragma unroll 4
        for (int c = 0; c < 20; ++c) {
            const bool eq = (myc == c);
            float v0 = eq ? a0.x : 0.f, v1 = eq ? a0.y : 0.f;
            float v2 = eq ? a0.z : 0.f, v3 = eq ? a0.w : 0.f;
            float v4 = eq ? a1.x : 0.f, v5 = eq ? a1.y : 0.f;
            float v6 = eq ? a1.z : 0.f, v7 = eq ? a1.w : 0.f;
            float cn = eq ? 1.f : 0.f;
            for (int off = 32; off; off >>= 1) {
                v0 += __shfl_xor(v0, off, 64); v1 += __shfl_xor(v1, off, 64);
                v2 += __shfl_xor(v2, off, 64); v3 += __shfl_xor(v3, off, 64);
                v4 += __shfl_xor(v4, off, 64); v5 += __shfl_xor(v5, off, 64);
                v6 += __shfl_xor(v6, off, 64); v7 += __shfl_xor(v7, off, 64);
                cn += __shfl_xor(cn, off, 64);
            }
            if (l == 0) {
                shs[w][c][0]=v0; shs[w][c][1]=v1; shs[w][c][2]=v2; shs[w][c][3]=v3;
                shs[w][c][4]=v4; shs[w][c][5]=v5; shs[w][c][6]=v6; shs[w][c][7]=v7;
                shc[w][c]=cn;
            }
        }
        __syncthreads();
        float* p2 = part2 + (size_t)(side * 16 + blk) * 192;
        if (t < 160) {
            const int c = t >> 3, o = t & 7;
            p2[t] = shs[0][c][o] + shs[1][c][o] + shs[2][c][o] + shs[3][c][o];
        } else if (t < 180) {
            const int c = t - 160;
            p2[160 + c] = shc[0][c] + shc[1][c] + shc[2][c] + shc[3][c];
        }
    }
}

// ---------------------------------------------------------------------------
// loss finisher: 4 blocks, no atomics; sums the 4 k-splits per j
// ---------------------------------------------------------------------------
__global__ __launch_bounds__(256) void loss_finish_kernel(
    const float* __restrict__ part, const float* __restrict__ part2,
    const float* __restrict__ A_roi_c, const float* __restrict__ A_rpn_c,
    const int* __restrict__ roi_class, const int* __restrict__ rpn_class,
    float* __restrict__ out)
{
    const int li = blockIdx.x, t = threadIdx.x;
    __shared__ float V[20][8];
    __shared__ float cnt[20];
    __shared__ float T[8];
    __shared__ float red[4];
    float s = 0.f;
    if (li < 2) {
        const float* A = (li == 0) ? A_roi_c : A_rpn_c;
        const int* cls = (li == 0) ? roi_class : rpn_class;
        const float* p2 = part2 + (size_t)li * 16 * 192;
        if (t < 160) {
            float sv = 0.f;
#pragma unroll
            for (int bb = 0; bb < 16; ++bb) sv += p2[bb * 192 + t];
            V[t >> 3][t & 7] = sv;
        } else if (t >= 192 && t < 212) {
            float cv = 0.f;
#pragma unroll
            for (int bb = 0; bb < 16; ++bb) cv += p2[bb * 192 + 160 + (t - 192)];
            cnt[t - 192] = cv;
        }
        __syncthreads();
        if (li == 0 && t < 160)
            out[16 + t] = V[t >> 3][t & 7] / fmaxf(cnt[t >> 3], 1.f);
        if (t < 8) {
            float tv = 0.f;
            for (int c = 0; c < 20; ++c) tv += V[c][t];
            T[t] = tv;
        }
        __syncthreads();
        if (t < 160) {
            const int c = t >> 3, o = t & 7;
            V[c][o] = T[o] + E2M1 * V[c][o];
        }
        __syncthreads();
#pragma unroll
        for (int u = 0; u < 16; ++u) {
            const int j = t * 16 + u;
            const int c = cls[j];
            const float m = cnt[c];
            const float Cg = (4096.f - m) + m * E2;
            const float4 a0 = *(const float4*)&A[(size_t)j * 8];
            const float4 a1 = *(const float4*)&A[(size_t)j * 8 + 4];
            const float U = a0.x*V[c][0] + a0.y*V[c][1] + a0.z*V[c][2] + a0.w*V[c][3]
                          + a1.x*V[c][4] + a1.y*V[c][5] + a1.z*V[c][6] + a1.w*V[c][7];
            const float* p = part + ((size_t)li * 4096 + j) * 12;
            const float Sxj = p[0] + p[3] + p[6] + p[9];
            s += (2.f * U - __logf(Sxj + NEPS) * Cg) / (Cg + NEPS);
        }
    } else {
#pragma unroll
        for (int u = 0; u < 16; ++u) {
            const int j = t * 16 + u;
            const float* p = part + ((size_t)li * 4096 + j) * 12;
            const float vx = p[0] + p[3] + p[6] + p[9];
            const float vg = p[1] + p[4] + p[7] + p[10];
            const float vu = p[2] + p[5] + p[8] + p[11];
            s += (2.f * vu - __logf(vx + NEPS) * vg) / (vg + NEPS);
        }
    }
    for (int off = 32; off; off >>= 1) s += __shfl_xor(s, off, 64);
    if ((t & 63) == 0) red[t >> 6] = s;
    __syncthreads();
    if (t == 0) out[184 + li] = -(red[0] + red[1] + red[2] + red[3]) / 4096.f;
}

// ---------------------------------------------------------------------------
extern "C" void kernel_launch(void* const* d_in, const int* in_sizes, int n_in,
                              void* d_out, int out_size, void* d_ws, size_t ws_size,
                              hipStream_t stream)
{
    const float* rpn_feat  = (const float*)d_in[0];
    const float* rpn_del   = (const float*)d_in[1];
    const float* rpn_scale = (const float*)d_in[2];
    const float* roi_feat  = (const float*)d_in[3];
    const float* roi_del   = (const float*)d_in[4];
    const float* roi_scale = (const float*)d_in[5];
    const int*   rpn_class = (const int*)d_in[6];
    const int*   roi_class = (const int*)d_in[7];
    const float* W_rpn_feat = (const float*)d_in[8];  const float* b_rpn_feat = (const float*)d_in[9];
    const float* W_rpn_del  = (const float*)d_in[10]; const float* b_rpn_del  = (const float*)d_in[11];
    const float* W_rpn_sc   = (const float*)d_in[12]; const float* b_rpn_sc   = (const float*)d_in[13];
    const float* W_roi_feat = (const float*)d_in[14]; const float* b_roi_feat = (const float*)d_in[15];
    const float* W_roi_del  = (const float*)d_in[16]; const float* b_roi_del  = (const float*)d_in[17];
    const float* W_roi_sc   = (const float*)d_in[18]; const float* b_roi_sc   = (const float*)d_in[19];
    const float* rpn_cls_W1  = (const float*)d_in[20]; const float* rpn_cls_b1  = (const float*)d_in[21];
    const float* rpn_cls_W2  = (const float*)d_in[22]; const float* rpn_cls_b2  = (const float*)d_in[23];
    const float* rpn_bbox_W1 = (const float*)d_in[24]; const float* rpn_bbox_b1 = (const float*)d_in[25];
    const float* rpn_bbox_W2 = (const float*)d_in[26]; const float* rpn_bbox_b2 = (const float*)d_in[27];
    const float* roi_cls_W1  = (const float*)d_in[28]; const float* roi_cls_b1  = (const float*)d_in[29];
    const float* roi_cls_W2  = (const float*)d_in[30]; const float* roi_cls_b2  = (const float*)d_in[31];
    const int* iter_ptr = (const int*)d_in[32];
    float* out = (float*)d_out;
    char*  wsb = (char*)d_ws;

    // ---- workspace layout ----
    unsigned short* roi_feat_sw = (unsigned short*)(wsb + 0);          // 4096x1024
    unsigned short* Ab_all      = (unsigned short*)(wsb + 0);          // launch 4+
    unsigned short* WfT_roi_c   = (unsigned short*)(wsb + 8388608);    // 1024x1024 (dead after comp)
    unsigned short* WfT_roi_b   = (unsigned short*)(wsb + 10485760);   // 1024x1024
    float*          part        = (float*)(wsb + 8388608);             // 4x4096x4x3 (launch 5+)
    unsigned short* comp_roi_c  = (unsigned short*)(wsb + 12582912);   // 256x1024
    unsigned short* comp_roi_b  = (unsigned short*)(wsb + 13107200);   // 256x1024
    unsigned short* comp_rpn_c  = (unsigned short*)(wsb + 13631488);   // 128x256
    unsigned short* comp_rpn_b  = (unsigned short*)(wsb + 13697024);   // 128x256
    float*          ext         = (float*)(wsb + 13762560);            // 4x1536 f32
    float*          zerobuf     = (float*)(wsb + 13787136);            // 1024 f32
    unsigned short* WfT_rpn_c   = (unsigned short*)(wsb + 13791232);   // 256x256
    unsigned short* WfT_rpn_b   = (unsigned short*)(wsb + 13922304);   // 256x256
    unsigned short* roi_W1_sw   = (unsigned short*)(wsb + 29360128);   // 256x1024
    unsigned short* h_roi_c     = (unsigned short*)(wsb + 29884416);   // 4096x256 linear
    unsigned short* h_roi_b     = (unsigned short*)(wsb + 31981568);   // 4096x256 linear
    unsigned short* rpn_feat_sw = (unsigned short*)(wsb + 34078720);   // 4096x256
    unsigned short* rpn_cW1_sw  = (unsigned short*)(wsb + 40632320);   // 128x256 padded
    unsigned short* rpn_bW1_sw  = (unsigned short*)(wsb + 40697856);   // 128x256 padded
    unsigned short* h_rpn_c     = (unsigned short*)(wsb + 40763392);   // 4096x128 linear
    unsigned short* h_rpn_b     = (unsigned short*)(wsb + 41811968);   // 4096x128 linear
    float* A_rpn_c = (float*)(wsb + 42861568);
    float* A_rpn_b = (float*)(wsb + 42992640);
    float* A_roi_c = (float*)(wsb + 43123712);
    float* A_roi_b = (float*)(wsb + 43254784);
    unsigned short* Db_roi = (unsigned short*)(wsb + 43385856);
    unsigned short* Db_rpn = (unsigned short*)(wsb + 43648000);
    float* part2 = (float*)(wsb + 43910144);                           // 32x192 f32

    // ---- 1: prep ----
    prep_kernel<<<dim3(3553), 256, 0, stream>>>(
        roi_feat, W_roi_feat, roi_cls_W1, rpn_feat, W_rpn_feat,
        rpn_cls_W1, rpn_bbox_W1, rpn_cls_b1, rpn_bbox_b1,
        roi_del, rpn_del,
        W_roi_del, W_roi_sc, b_roi_feat, b_roi_del, b_roi_sc, roi_cls_b1,
        W_rpn_del, W_rpn_sc, b_rpn_feat, b_rpn_del, b_rpn_sc,
        roi_feat_sw, WfT_roi_c, WfT_roi_b, roi_W1_sw, rpn_feat_sw,
        WfT_rpn_c, WfT_rpn_b, rpn_cW1_sw, rpn_bW1_sw,
        Db_roi, Db_rpn, ext, zerobuf, out);

    // ---- 2: composite weights comp = W1 @ Wf_half (144 wave-blocks) ----
    {
        GemmJobs js;
        js.n = 4;
        js.j[0] = { roi_W1_sw,  WfT_roi_c, comp_roi_c, zerobuf,
                    nullptr, nullptr, nullptr, nullptr, nullptr, nullptr,
                    8192, 32768, 16, 0, 1024, 16, 0 };
        // reference bug: roi bbox half also uses roi_cls_W1
        js.j[1] = { roi_W1_sw,  WfT_roi_b, comp_roi_b, zerobuf,
                    nullptr, nullptr, nullptr, nullptr, nullptr, nullptr,
                    8192, 32768, 16, 0, 1024, 16, 64 };
        js.j[2] = { rpn_cW1_sw, WfT_rpn_c, comp_rpn_c, zerobuf,
                    nullptr, nullptr, nullptr, nullptr, nullptr, nullptr,
                    4096, 8192, 8, 0, 256, 4, 128 };
        js.j[3] = { rpn_bW1_sw, WfT_rpn_b, comp_rpn_b, zerobuf,
                    nullptr, nullptr, nullptr, nullptr, nullptr, nullptr,
                    4096, 8192, 8, 0, 256, 4, 136 };
        gemm_reg<false, true, false><<<dim3(144), 64, 0, stream>>>(js);
    }

    // ---- 3: main GEMM h = relu(X@comp^T + extras) (768 wave-blocks) ----
    {
        GemmJobs js;
        js.n = 4;
        js.j[0] = { roi_feat_sw, comp_roi_c, h_roi_c, ext + 0 * 1536 + 1280,
                    roi_del, ext + 0 * 1536, zerobuf, roi_scale, ext + 0 * 1536 + 1024, zerobuf,
                    131072, 8192, 0, 256, 1024, 4, 0 };
        js.j[1] = { roi_feat_sw, comp_roi_b, h_roi_b, ext + 1 * 1536 + 1280,
                    roi_del, ext + 1 * 1536, zerobuf, roi_scale, ext + 1 * 1536 + 1024, zerobuf,
                    131072, 8192, 0, 256, 1024, 4, 256 };
        js.j[2] = { rpn_feat_sw, comp_rpn_c, h_rpn_c, ext + 2 * 1536 + 1280,
                    rpn_del, ext + 2 * 1536, zerobuf, rpn_scale, ext + 2 * 1536 + 1024, zerobuf,
                    131072, 4096, 0, 128, 256, 2, 512 };
        js.j[3] = { rpn_feat_sw, comp_rpn_b, h_rpn_b, ext + 3 * 1536 + 1280,
                    rpn_del, ext + 3 * 1536, zerobuf, rpn_scale, ext + 3 * 1536 + 1024, zerobuf,
                    131072, 4096, 0, 128, 256, 2, 640 };
        gemm_reg<true, false, true><<<dim3(768), 64, 0, stream>>>(js);
    }

    // ---- 4: all 4 alphas ----
    alphas_all<<<dim3(4096), 256, 0, stream>>>(
        h_rpn_c, h_rpn_b, h_roi_c, h_roi_b,
        rpn_cls_W2, rpn_bbox_W2, roi_cls_W2,
        rpn_cls_b2, rpn_bbox_b2, roi_cls_b2,
        iter_ptr, A_rpn_c, A_rpn_b, A_roi_c, A_roi_b, Ab_all);

    // ---- 5: k-split loss pair-pass + means + class-sum partials ----
    finale_kernel<<<dim3(2083), 256, 0, stream>>>(
        Ab_all, Db_roi, Db_rpn,
        A_roi_c, A_rpn_c, A_roi_b, A_rpn_b,
        roi_class, rpn_class, part, part2, out);

    // ---- 6: loss finish ----
    loss_finish_kernel<<<dim3(4), 256, 0, stream>>>(
        part, part2, A_roi_c, A_rpn_c, roi_class, rpn_class, out);
}

// Round 20
// 101.991 us; speedup vs baseline: 1.1038x; 1.1038x over previous
//
#include <hip/hip_runtime.h>
#include <math.h>

#define NPTS 4096
#define NEPS 4.096e-4f                 // 4096 * 1e-7
#define E2   7.3890560989306495f       // exp(2)
#define E2M1 6.3890560989306495f       // exp(2) - 1

typedef float  f32x4 __attribute__((ext_vector_type(4)));
typedef short  s16x8 __attribute__((ext_vector_type(8)));

static __device__ __forceinline__ unsigned short f2b(float x) {
    unsigned u = __builtin_bit_cast(unsigned, x);
    return (unsigned short)((u + 0x7fffu + ((u >> 16) & 1u)) >> 16);
}
static __device__ __forceinline__ float b2f(unsigned short h) {
    return __builtin_bit_cast(float, (unsigned)h << 16);
}

// fragment-order (swizzled) element offset for element (r,c) of an R-row matrix
static __device__ __forceinline__ size_t swz(int r, int c, int R16) {
    return (((size_t)((c >> 5) * R16 + (r >> 4))) << 9)
         + ((size_t)((r & 15) + (((c & 31) >> 3) << 4)) << 3) + (c & 7);
}

// ---------------------------------------------------------------------------
// prep (3553 blocks)
// ---------------------------------------------------------------------------
__global__ __launch_bounds__(256) void prep_kernel(
    const float* __restrict__ roi_feat, const float* __restrict__ W_roi_feat,
    const float* __restrict__ roi_cls_W1,
    const float* __restrict__ rpn_feat, const float* __restrict__ W_rpn_feat,
    const float* __restrict__ rpn_cls_W1, const float* __restrict__ rpn_bbox_W1,
    const float* __restrict__ rpn_cls_b1, const float* __restrict__ rpn_bbox_b1,
    const float* __restrict__ roi_del, const float* __restrict__ rpn_del,
    const float* __restrict__ W_roi_del, const float* __restrict__ W_roi_sc,
    const float* __restrict__ b_roi_feat, const float* __restrict__ b_roi_del,
    const float* __restrict__ b_roi_sc,  const float* __restrict__ roi_cls_b1v,
    const float* __restrict__ W_rpn_del, const float* __restrict__ W_rpn_sc,
    const float* __restrict__ b_rpn_feat, const float* __restrict__ b_rpn_del,
    const float* __restrict__ b_rpn_sc,
    unsigned short* __restrict__ roi_feat_sw,
    unsigned short* __restrict__ WfT_roi_c, unsigned short* __restrict__ WfT_roi_b,
    unsigned short* __restrict__ roi_W1_sw,
    unsigned short* __restrict__ rpn_feat_sw,
    unsigned short* __restrict__ WfT_rpn_c, unsigned short* __restrict__ WfT_rpn_b,
    unsigned short* __restrict__ rpn_cW1_sw, unsigned short* __restrict__ rpn_bW1_sw,
    unsigned short* __restrict__ Db_roi, unsigned short* __restrict__ Db_rpn,
    float* __restrict__ ext, float* __restrict__ zerobuf,
    float* __restrict__ out)
{
    const int b = blockIdx.x, t = threadIdx.x;
    if (b < 2688) {
        const float* in; unsigned short* o; int base, cshift, R16;
        if      (b < 2048) { in = roi_feat;   o = roi_feat_sw; base = b;        cshift = 10; R16 = 256; }
        else if (b < 2176) { in = roi_cls_W1; o = roi_W1_sw;   base = b - 2048; cshift = 10; R16 = 16;  }
        else               { in = rpn_feat;   o = rpn_feat_sw; base = b - 2176; cshift = 8;  R16 = 256; }
        const int i = base * 2048 + t * 8;
        const int r = i >> cshift, c = i & ((1 << cshift) - 1);
        const float4 v0 = *(const float4*)&in[i];
        const float4 v1 = *(const float4*)&in[i + 4];
        s16x8 pk;
        pk[0] = (short)f2b(v0.x); pk[1] = (short)f2b(v0.y);
        pk[2] = (short)f2b(v0.z); pk[3] = (short)f2b(v0.w);
        pk[4] = (short)f2b(v1.x); pk[5] = (short)f2b(v1.y);
        pk[6] = (short)f2b(v1.z); pk[7] = (short)f2b(v1.w);
        *(s16x8*)(o + swz(r, c, R16)) = pk;
    } else if (b < 2720) {
        const bool cls = b < 2704;
        const float* W = cls ? rpn_cls_W1 : rpn_bbox_W1;
        unsigned short* o = cls ? rpn_cW1_sw : rpn_bW1_sw;
        const int local = b - (cls ? 2688 : 2704);
        const int i = local * 2048 + t * 8;
        const int r = i >> 8, c = i & 255;
        s16x8 pk;
#pragma unroll
        for (int u = 0; u < 8; ++u)
            pk[u] = (r < 64) ? (short)f2b(W[r * 256 + c + u]) : (short)0;
        *(s16x8*)(o + swz(r, c, 8)) = pk;
    } else if (b < 2752) {
        const int row = (b - 2720) * 256 + t;
        const int mat = row >> 12, r = row & 4095;
        const float* D = mat ? rpn_del : roi_del;
        unsigned short* o = mat ? Db_rpn : Db_roi;
        const float4 dv = *(const float4*)&D[(size_t)r * 4];
        ushort4 d4; d4.x = f2b(dv.x); d4.y = f2b(dv.y); d4.z = f2b(dv.z); d4.w = f2b(dv.w);
        unsigned short* p = o + (size_t)r * 32;
        ushort4 z4 = {0, 0, 0, 0};
        *(ushort4*)p = d4;
        *(ushort4*)(p + 4)  = z4;
        *(ushort4*)(p + 8)  = z4; *(ushort4*)(p + 12) = z4;
        *(ushort4*)(p + 16) = z4; *(ushort4*)(p + 20) = z4;
        *(ushort4*)(p + 24) = z4; *(ushort4*)(p + 28) = z4;
    } else if (b < 3008) {
        const int e = b - 2752;
        const int job = e >> 6;
        const int w = t >> 6, l = t & 63;
        const int hl = (e & 63) * 4 + w;
        const float *W1, *Wd, *Wsc, *bA, *bB, *bC, *b1;
        int K, ooff, Hact, Htot;
        if (job == 0)      { W1 = roi_cls_W1;  K = 1024; ooff = 0;    Wd = W_roi_del; Wsc = W_roi_sc; bA = b_roi_feat; bB = b_roi_del; bC = b_roi_sc; b1 = roi_cls_b1v; Hact = 256; Htot = 256; }
        else if (job == 1) { W1 = roi_cls_W1;  K = 1024; ooff = 1024; Wd = W_roi_del; Wsc = W_roi_sc; bA = b_roi_feat; bB = b_roi_del; bC = b_roi_sc; b1 = roi_cls_b1v; Hact = 256; Htot = 256; }
        else if (job == 2) { W1 = rpn_cls_W1;  K = 256;  ooff = 0;    Wd = W_rpn_del; Wsc = W_rpn_sc; bA = b_rpn_feat; bB = b_rpn_del; bC = b_rpn_sc; b1 = rpn_cls_b1;  Hact = 64;  Htot = 128; }
        else               { W1 = rpn_bbox_W1; K = 256;  ooff = 256;  Wd = W_rpn_del; Wsc = W_rpn_sc; bA = b_rpn_feat; bB = b_rpn_del; bC = b_rpn_sc; b1 = rpn_bbox_b1; Hact = 64;  Htot = 128; }
        if (hl >= Htot) return;
        float a0 = 0.f, a1 = 0.f, a2 = 0.f, a3 = 0.f, a4 = 0.f, a5 = 0.f;
        if (hl < Hact) {
            for (int o = l; o < K; o += 64) {
                const float wv = W1[hl * K + o];
                const float4 wd = *(const float4*)&Wd[(ooff + o) * 4];
                a0 = fmaf(wv, wd.x, a0); a1 = fmaf(wv, wd.y, a1);
                a2 = fmaf(wv, wd.z, a2); a3 = fmaf(wv, wd.w, a3);
                a4 = fmaf(wv, Wsc[ooff + o], a4);
                a5 = fmaf(wv, bA[ooff + o] + bB[ooff + o] + bC[ooff + o], a5);
            }
            for (int off = 32; off; off >>= 1) {
                a0 += __shfl_xor(a0, off, 64); a1 += __shfl_xor(a1, off, 64);
                a2 += __shfl_xor(a2, off, 64); a3 += __shfl_xor(a3, off, 64);
                a4 += __shfl_xor(a4, off, 64); a5 += __shfl_xor(a5, off, 64);
            }
        }
        if (l == 0) {
            float* ej = ext + job * 1536;
            ej[hl * 4 + 0] = a0; ej[hl * 4 + 1] = a1;
            ej[hl * 4 + 2] = a2; ej[hl * 4 + 3] = a3;
            ej[1024 + hl] = a4;
            ej[1280 + hl] = (hl < Hact) ? (a5 + b1[hl]) : 0.f;
        }
    } else if (b < 3552) {
        __shared__ __align__(16) unsigned short ldsT[64][72];
        const float* src; unsigned short* dst;
        int ld, R16, o0g, o_loc0, c0;
        if (b < 3520) {
            const int tt = b - 3008;
            const int half = tt >> 8, tile = tt & 255;
            const int ot = tile & 15, ct = tile >> 4;
            src = W_roi_feat; ld = 1024; R16 = 64;
            o0g = half * 1024 + ot * 64; o_loc0 = ot * 64; c0 = ct * 64;
            dst = half ? WfT_roi_b : WfT_roi_c;
        } else {
            const int tt = b - 3520;
            const int half = tt >> 4, tile = tt & 15;
            const int ot = tile & 3, ct = tile >> 2;
            src = W_rpn_feat; ld = 256; R16 = 16;
            o0g = half * 256 + ot * 64; o_loc0 = ot * 64; c0 = ct * 64;
            dst = half ? WfT_rpn_b : WfT_rpn_c;
        }
        const int r = t >> 2, cg = (t & 3) << 4;
        const float* sp = src + (size_t)(o0g + r) * ld + c0 + cg;
        const float4 v0 = *(const float4*)(sp + 0);
        const float4 v1 = *(const float4*)(sp + 4);
        const float4 v2 = *(const float4*)(sp + 8);
        const float4 v3 = *(const float4*)(sp + 12);
        const float vv[16] = {v0.x,v0.y,v0.z,v0.w, v1.x,v1.y,v1.z,v1.w,
                              v2.x,v2.y,v2.z,v2.w, v3.x,v3.y,v3.z,v3.w};
#pragma unroll
        for (int k = 0; k < 16; ++k)
            ldsT[cg + k][r] = f2b(vv[k]);
        __syncthreads();
#pragma unroll
        for (int qq = 0; qq < 2; ++qq) {
            const int q = t + qq * 256;
            const int s = q >> 6, l = q & 63;
            const int kj = s & 1, si = s >> 1;
            const int cl = si * 16 + (l & 15);
            const int ol = kj * 32 + ((l >> 4) << 3);
            const s16x8 val = *(const s16x8*)&ldsT[cl][ol];
            const size_t base = ((size_t)(((o_loc0 >> 5) + kj) * R16 + (c0 >> 4) + si)) << 9;
            *(s16x8*)(dst + base + l * 8) = val;
        }
    } else {
        *(float4*)&zerobuf[t * 4] = float4{0.f, 0.f, 0.f, 0.f};
        if (t < 4) out[184 + t] = 0.f;
    }
}

// ---------------------------------------------------------------------------
// Register-direct MFMA GEMM, WAVE-PER-BLOCK (64 thr, one 64x64 tile), depth-4.
// ---------------------------------------------------------------------------
struct GemmJob {
    const unsigned short *A, *W;
    unsigned short *C;
    const float *bias;
    const float *del, *Wd, *bd, *sc, *Wsc, *bs;
    int strideA, strideB;
    int M16;
    int ldc;
    int K, nbx, bstart;
};
struct GemmJobs { GemmJob j[4]; int n; };

#define LDSET(Av, Bv)                                          \
    {                                                          \
        _Pragma("unroll")                                      \
        for (int m = 0; m < 4; ++m) {                          \
            Av[m] = *(const s16x8*)(pa + (m << 9));            \
            Bv[m] = *(const s16x8*)(pb + (m << 9));            \
        }                                                      \
        pa += jb.strideA; pb += jb.strideB;                    \
    }

#define MMSET(Av, Bv)                                          \
    {                                                          \
        _Pragma("unroll")                                      \
        for (int m = 0; m < 4; ++m)                            \
            _Pragma("unroll")                                  \
            for (int n = 0; n < 4; ++n)                        \
                acc[m][n] = __builtin_amdgcn_mfma_f32_16x16x32_bf16( \
                    Av[m], Bv[n], acc[m][n], 0, 0, 0);         \
    }

template<bool EXTRAS, bool CSWZ, bool RELU>
__global__ __launch_bounds__(64) void gemm_reg(GemmJobs jobs)
{
    const int bid = blockIdx.x;
    int ji = 0;
#pragma unroll
    for (int i = 1; i < 4; ++i)
        if (i < jobs.n && bid >= jobs.j[i].bstart) ji = i;
    const GemmJob jb = jobs.j[ji];
    const int local = bid - jb.bstart;
    const int bx = local % jb.nbx, by = local / jb.nbx;

    const int l = threadIdx.x & 63;
    const int fr = l & 15, fq = l >> 4;

    const int sA0 = by * 4;
    const int sB0 = bx * 4;
    const unsigned short* pa = jb.A + ((size_t)sA0 << 9) + (size_t)(l * 8);
    const unsigned short* pb = jb.W + ((size_t)sB0 << 9) + (size_t)(l * 8);

    f32x4 acc[4][4] = {};
    s16x8 A0[4], B0[4], A1[4], B1[4], A2[4], B2[4], A3[4], B3[4];

    const int niter = jb.K >> 5;
    LDSET(A0, B0);
    LDSET(A1, B1);
    LDSET(A2, B2);

    for (int it = 0; it < niter; it += 4) {
        if (it + 3 < niter) LDSET(A3, B3);
        MMSET(A0, B0);
        if (it + 4 < niter) LDSET(A0, B0);
        MMSET(A1, B1);
        if (it + 5 < niter) LDSET(A1, B1);
        MMSET(A2, B2);
        if (it + 6 < niter) LDSET(A2, B2);
        MMSET(A3, B3);
    }

#pragma unroll
    for (int n = 0; n < 4; ++n) {
        const int cc = (sB0 + n) * 16 + fr;
        float cadd = jb.bias[cc];
        float wd0 = 0.f, wd1 = 0.f, wd2 = 0.f, wd3 = 0.f, wscv = 0.f;
        if (EXTRAS) {
            cadd += jb.bd[cc] + jb.bs[cc];
            const float4 w4 = *(const float4*)&jb.Wd[cc * 4];
            wd0 = w4.x; wd1 = w4.y; wd2 = w4.z; wd3 = w4.w;
            wscv = jb.Wsc[cc];
        }
#pragma unroll
        for (int m = 0; m < 4; ++m) {
            const int si = sA0 + m;
            unsigned short* cp;
            if (CSWZ) {
                const int kj = cc >> 5;
                cp = jb.C + (((size_t)(kj * jb.M16 + si)) << 9)
                   + (((size_t)((cc & 31) >> 3)) << 7) + (cc & 7);
            }
#pragma unroll
            for (int j = 0; j < 4; ++j) {
                const int rr = fq * 4 + j;
                const int row = si * 16 + rr;
                float v = acc[m][n][j] + cadd;
                if (EXTRAS) {
                    const float4 dm = *(const float4*)&jb.del[row * 4];
                    v += dm.x * wd0 + dm.y * wd1 + dm.z * wd2 + dm.w * wd3
                       + jb.sc[row] * wscv;
                }
                if (RELU) v = fmaxf(v, 0.f);
                if (CSWZ) cp[(size_t)rr << 3] = f2b(v);
                else      jb.C[(size_t)row * jb.ldc + cc] = f2b(v);
            }
        }
    }
}

// ---------------------------------------------------------------------------
// alphas for all 4 matrices
// ---------------------------------------------------------------------------
__global__ __launch_bounds__(256) void alphas_all(
    const unsigned short* __restrict__ h_rpn_c, const unsigned short* __restrict__ h_rpn_b,
    const unsigned short* __restrict__ h_roi_c, const unsigned short* __restrict__ h_roi_b,
    const float* __restrict__ W2_rc, const float* __restrict__ W2_rb,
    const float* __restrict__ W2_oc,
    const float* __restrict__ b2_rc, const float* __restrict__ b2_rb,
    const float* __restrict__ b2_oc,
    const int* __restrict__ iter_ptr,
    float* __restrict__ A_rpn_c, float* __restrict__ A_rpn_b,
    float* __restrict__ A_roi_c, float* __restrict__ A_roi_b,
    unsigned short* __restrict__ Ab_all)
{
    const int vrow = blockIdx.x * 4 + (threadIdx.x >> 6);
    const int mat = vrow >> 12, row = vrow & 4095;
    const unsigned short* H; const float *W2, *b2; float* Ao; int ldh, Hd;
    if (mat == 0)      { H = h_rpn_c; W2 = W2_rc; b2 = b2_rc; Ao = A_rpn_c; ldh = 128; Hd = 64; }
    else if (mat == 1) { H = h_rpn_b; W2 = W2_rb; b2 = b2_rb; Ao = A_rpn_b; ldh = 128; Hd = 64; }
    else if (mat == 2) { H = h_roi_c; W2 = W2_oc; b2 = b2_oc; Ao = A_roi_c; ldh = 256; Hd = 256; }
    else               { H = h_roi_b; W2 = W2_oc; b2 = b2_oc; Ao = A_roi_b; ldh = 256; Hd = 256; }

    const int l = threadIdx.x & 63;
    float acc[8] = {};
    for (int m = l * 4; m < Hd; m += 256) {
        const ushort4 h4 = *(const ushort4*)&H[(size_t)row * ldh + m];
        const float h0 = b2f(h4.x), h1 = b2f(h4.y), h2 = b2f(h4.z), h3 = b2f(h4.w);
#pragma unroll
        for (int o = 0; o < 8; ++o) {
            const float4 w4 = *(const float4*)&W2[o * Hd + m];
            acc[o] += h0 * w4.x + h1 * w4.y + h2 * w4.z + h3 * w4.w;
        }
    }
#pragma unroll
    for (int o = 0; o < 8; ++o)
        for (int off = 32; off; off >>= 1)
            acc[o] += __shfl_xor(acc[o], off, 64);

    const int it = *iter_ptr;
    const float temp = fmaxf(1.0f, 30.0f * (float)(90000 - it) / 90000.0f);
    float lg[8], mx = -1e30f;
#pragma unroll
    for (int o = 0; o < 8; ++o) { lg[o] = (acc[o] + b2[o]) / temp; mx = fmaxf(mx, lg[o]); }
    float s = 0.f;
#pragma unroll
    for (int o = 0; o < 8; ++o) { lg[o] = __expf(lg[o] - mx); s += lg[o]; }
    const float inv = 1.0f / s;
    if (l < 8) Ao[(size_t)row * 8 + l] = lg[l] * inv;
    unsigned short* Ab = Ab_all + (size_t)mat * 131072 + (size_t)row * 32;
    if (l == 0) {
        ushort4 o0, o1;
        o0.x = f2b(lg[0]*inv); o0.y = f2b(lg[1]*inv); o0.z = f2b(lg[2]*inv); o0.w = f2b(lg[3]*inv);
        o1.x = f2b(lg[4]*inv); o1.y = f2b(lg[5]*inv); o1.z = f2b(lg[6]*inv); o1.w = f2b(lg[7]*inv);
        *(ushort4*)Ab = o0; *(ushort4*)(Ab + 4) = o1;
    } else if (l < 4) {
        ushort4 z = {0,0,0,0};
        *(ushort4*)(Ab + l * 8)     = z;
        *(ushort4*)(Ab + l * 8 + 4) = z;
    }
}

// ---------------------------------------------------------------------------
// finale (547 blocks): loss pair-pass + means + class-sum partials (no atomics)
// ---------------------------------------------------------------------------
__global__ __launch_bounds__(256) void finale_kernel(
    const unsigned short* __restrict__ Ab_all,
    const unsigned short* __restrict__ Db_roi, const unsigned short* __restrict__ Db_rpn,
    const float* __restrict__ A_roi_c, const float* __restrict__ A_rpn_c,
    const float* __restrict__ A_roi_b, const float* __restrict__ A_rpn_b,
    const int* __restrict__ roi_class, const int* __restrict__ rpn_class,
    float* __restrict__ part, float* __restrict__ part2, float* __restrict__ out)
{
    const int b = blockIdx.x, t = threadIdx.x;
    const int w = t >> 6, l = t & 63;
    const int fr = l & 15, fq = l >> 4;

    if (b < 512) {
        __shared__ float sh[4][2][16][3];
        const int li = b >> 7;
        const int blk = b & 127;
        const int j0 = blk * 32;
        const bool is_cls = li < 2;
        const int mat = (li == 0) ? 2 : (li == 1) ? 0 : (li == 2) ? 3 : 1;
        const unsigned short* Ab = Ab_all + (size_t)mat * 131072;
        const unsigned short* Db = (li == 2) ? Db_roi : Db_rpn;

        s16x8 bj[2], dj[2];
#pragma unroll
        for (int jt = 0; jt < 2; ++jt) {
            const int j = j0 + jt * 16;
            bj[jt] = *(const s16x8*)&Ab[(size_t)(j + fr) * 32 + fq * 8];
            if (!is_cls) dj[jt] = *(const s16x8*)&Db[(size_t)(j + fr) * 32 + fq * 8];
        }

        float Sx[2] = {}, Sg[2] = {}, U[2] = {};
        const int kbase0 = w * 1024;
        const f32x4 zc = {0.f, 0.f, 0.f, 0.f};

        if (is_cls) {
            for (int ob = 0; ob < 8; ++ob) {
                const int kb0 = kbase0 + ob * 128;
                s16x8 af[8];
#pragma unroll
                for (int u = 0; u < 8; ++u)
                    af[u] = *(const s16x8*)&Ab[(size_t)(kb0 + u * 16 + fr) * 32 + fq * 8];
                f32x4 g[8][2];
#pragma unroll
                for (int u = 0; u < 8; ++u)
#pragma unroll
                    for (int jt = 0; jt < 2; ++jt)
                        g[u][jt] = __builtin_amdgcn_mfma_f32_16x16x32_bf16(af[u], bj[jt], zc, 0, 0, 0);
#pragma unroll
                for (int u = 0; u < 8; ++u)
#pragma unroll
                    for (int jt = 0; jt < 2; ++jt)
#pragma unroll
                        for (int r = 0; r < 4; ++r)
                            Sx[jt] += __expf(2.f * g[u][jt][r]);
            }
        } else {
            for (int ob = 0; ob < 16; ++ob) {
                const int kb0 = kbase0 + ob * 64;
                s16x8 af[4], df[4];
#pragma unroll
                for (int u = 0; u < 4; ++u) {
                    af[u] = *(const s16x8*)&Ab[(size_t)(kb0 + u * 16 + fr) * 32 + fq * 8];
                    df[u] = *(const s16x8*)&Db[(size_t)(kb0 + u * 16 + fr) * 32 + fq * 8];
                }
                f32x4 g[4][2], gd[4][2];
#pragma unroll
                for (int u = 0; u < 4; ++u)
#pragma unroll
                    for (int jt = 0; jt < 2; ++jt) {
                        g[u][jt]  = __builtin_amdgcn_mfma_f32_16x16x32_bf16(af[u], bj[jt], zc, 0, 0, 0);
                        gd[u][jt] = __builtin_amdgcn_mfma_f32_16x16x32_bf16(df[u], dj[jt], zc, 0, 0, 0);
                    }
#pragma unroll
                for (int u = 0; u < 4; ++u)
#pragma unroll
                    for (int jt = 0; jt < 2; ++jt)
#pragma unroll
                        for (int r = 0; r < 4; ++r) {
                            const float gv = g[u][jt][r];
                            const float ed = __expf(2.f * gd[u][jt][r]);
                            Sx[jt] += __expf(2.f * gv);
                            Sg[jt] += ed;
                            U[jt] = fmaf(ed, gv, U[jt]);
                        }
            }
        }

#pragma unroll
        for (int jt = 0; jt < 2; ++jt) {
            float vx = Sx[jt], vg = Sg[jt], vu = U[jt];
            for (int off = 16; off <= 32; off <<= 1) {
                vx += __shfl_xor(vx, off, 64);
                vg += __shfl_xor(vg, off, 64);
                vu += __shfl_xor(vu, off, 64);
            }
            if (fq == 0) {
                sh[w][jt][fr][0] = vx; sh[w][jt][fr][1] = vg; sh[w][jt][fr][2] = vu;
            }
        }
        __syncthreads();
        if (t < 32) {
            const int jt = t >> 4, jl = t & 15;
            float vx = 0.f, vg = 0.f, vu = 0.f;
#pragma unroll
            for (int wv = 0; wv < 4; ++wv) {
                vx += sh[wv][jt][jl][0]; vg += sh[wv][jt][jl][1]; vu += sh[wv][jt][jl][2];
            }
            const int j = j0 + jt * 16 + jl;
            float* p = part + ((size_t)li * 4096 + j) * 3;
            p[0] = vx; p[1] = vg; p[2] = vu;
        }
    } else if (b < 515) {
        __shared__ float S4[4][8];
        const float* A = (b == 512) ? A_rpn_c : (b == 513) ? A_rpn_b : A_roi_b;
        const int off0 = (b == 512) ? 0 : (b == 513) ? 8 : 176;
        float acc[8] = {};
        for (int r = t; r < NPTS; r += 256) {
            const float4 v0 = *(const float4*)&A[(size_t)r * 8];
            const float4 v1 = *(const float4*)&A[(size_t)r * 8 + 4];
            acc[0]+=v0.x; acc[1]+=v0.y; acc[2]+=v0.z; acc[3]+=v0.w;
            acc[4]+=v1.x; acc[5]+=v1.y; acc[6]+=v1.z; acc[7]+=v1.w;
        }
#pragma unroll
        for (int o = 0; o < 8; ++o) {
            float v = acc[o];
            for (int offs = 32; offs; offs >>= 1) v += __shfl_xor(v, offs, 64);
            if (l == 0) S4[w][o] = v;
        }
        __syncthreads();
        if (t < 8) {
            const float s = S4[0][t] + S4[1][t] + S4[2][t] + S4[3][t];
            out[off0 + t] = s * (1.f / 4096.f);
        }
    } else {
        __shared__ float shs[4][20][8];
        __shared__ float shc[4][20];
        const int local = b - 515;
        const int side = local >> 4, blk = local & 15;
        const float* A = side ? A_rpn_c : A_roi_c;
        const int* cls = side ? rpn_class : roi_class;
        const int row = blk * 256 + t;
        const float4 a0 = *(const float4*)&A[(size_t)row * 8];
        const float4 a1 = *(const float4*)&A[(size_t)row * 8 + 4];
        const int myc = cls[row];
#pragma unroll 4
        for (int c = 0; c < 20; ++c) {
            const bool eq = (myc == c);
            float v0 = eq ? a0.x : 0.f, v1 = eq ? a0.y : 0.f;
            float v2 = eq ? a0.z : 0.f, v3 = eq ? a0.w : 0.f;
            float v4 = eq ? a1.x : 0.f, v5 = eq ? a1.y : 0.f;
            float v6 = eq ? a1.z : 0.f, v7 = eq ? a1.w : 0.f;
            float cn = eq ? 1.f : 0.f;
            for (int off = 32; off; off >>= 1) {
                v0 += __shfl_xor(v0, off, 64); v1 += __shfl_xor(v1, off, 64);
                v2 += __shfl_xor(v2, off, 64); v3 += __shfl_xor(v3, off, 64);
                v4 += __shfl_xor(v4, off, 64); v5 += __shfl_xor(v5, off, 64);
                v6 += __shfl_xor(v6, off, 64); v7 += __shfl_xor(v7, off, 64);
                cn += __shfl_xor(cn, off, 64);
            }
            if (l == 0) {
                shs[w][c][0]=v0; shs[w][c][1]=v1; shs[w][c][2]=v2; shs[w][c][3]=v3;
                shs[w][c][4]=v4; shs[w][c][5]=v5; shs[w][c][6]=v6; shs[w][c][7]=v7;
                shc[w][c]=cn;
            }
        }
        __syncthreads();
        float* p2 = part2 + (size_t)(side * 16 + blk) * 192;
        if (t < 160) {
            const int c = t >> 3, o = t & 7;
            p2[t] = shs[0][c][o] + shs[1][c][o] + shs[2][c][o] + shs[3][c][o];
        } else if (t < 180) {
            const int c = t - 160;
            p2[160 + c] = shc[0][c] + shc[1][c] + shc[2][c] + shc[3][c];
        }
    }
}

// ---------------------------------------------------------------------------
// loss finisher: 4 blocks, no atomics
// ---------------------------------------------------------------------------
__global__ __launch_bounds__(256) void loss_finish_kernel(
    const float* __restrict__ part, const float* __restrict__ part2,
    const float* __restrict__ A_roi_c, const float* __restrict__ A_rpn_c,
    const int* __restrict__ roi_class, const int* __restrict__ rpn_class,
    float* __restrict__ out)
{
    const int li = blockIdx.x, t = threadIdx.x;
    __shared__ float V[20][8];
    __shared__ float cnt[20];
    __shared__ float T[8];
    __shared__ float red[4];
    float s = 0.f;
    if (li < 2) {
        const float* A = (li == 0) ? A_roi_c : A_rpn_c;
        const int* cls = (li == 0) ? roi_class : rpn_class;
        const float* p2 = part2 + (size_t)li * 16 * 192;
        if (t < 160) {
            float sv = 0.f;
#pragma unroll
            for (int bb = 0; bb < 16; ++bb) sv += p2[bb * 192 + t];
            V[t >> 3][t & 7] = sv;
        } else if (t >= 192 && t < 212) {
            float cv = 0.f;
#pragma unroll
            for (int bb = 0; bb < 16; ++bb) cv += p2[bb * 192 + 160 + (t - 192)];
            cnt[t - 192] = cv;
        }
        __syncthreads();
        if (li == 0 && t < 160)
            out[16 + t] = V[t >> 3][t & 7] / fmaxf(cnt[t >> 3], 1.f);
        if (t < 8) {
            float tv = 0.f;
            for (int c = 0; c < 20; ++c) tv += V[c][t];
            T[t] = tv;
        }
        __syncthreads();
        if (t < 160) {
            const int c = t >> 3, o = t & 7;
            V[c][o] = T[o] + E2M1 * V[c][o];
        }
        __syncthreads();
#pragma unroll
        for (int u = 0; u < 16; ++u) {
            const int j = t * 16 + u;
            const int c = cls[j];
            const float m = cnt[c];
            const float Cg = (4096.f - m) + m * E2;
            const float4 a0 = *(const float4*)&A[(size_t)j * 8];
            const float4 a1 = *(const float4*)&A[(size_t)j * 8 + 4];
            const float U = a0.x*V[c][0] + a0.y*V[c][1] + a0.z*V[c][2] + a0.w*V[c][3]
                          + a1.x*V[c][4] + a1.y*V[c][5] + a1.z*V[c][6] + a1.w*V[c][7];
            const float Sxj = part[((size_t)li * 4096 + j) * 3];
            s += (2.f * U - __logf(Sxj + NEPS) * Cg) / (Cg + NEPS);
        }
    } else {
#pragma unroll
        for (int u = 0; u < 16; ++u) {
            const int j = t * 16 + u;
            const float* p = part + ((size_t)li * 4096 + j) * 3;
            s += (2.f * p[2] - __logf(p[0] + NEPS) * p[1]) / (p[1] + NEPS);
        }
    }
    for (int off = 32; off; off >>= 1) s += __shfl_xor(s, off, 64);
    if ((t & 63) == 0) red[t >> 6] = s;
    __syncthreads();
    if (t == 0) out[184 + li] = -(red[0] + red[1] + red[2] + red[3]) / 4096.f;
}

// ---------------------------------------------------------------------------
extern "C" void kernel_launch(void* const* d_in, const int* in_sizes, int n_in,
                              void* d_out, int out_size, void* d_ws, size_t ws_size,
                              hipStream_t stream)
{
    const float* rpn_feat  = (const float*)d_in[0];
    const float* rpn_del   = (const float*)d_in[1];
    const float* rpn_scale = (const float*)d_in[2];
    const float* roi_feat  = (const float*)d_in[3];
    const float* roi_del   = (const float*)d_in[4];
    const float* roi_scale = (const float*)d_in[5];
    const int*   rpn_class = (const int*)d_in[6];
    const int*   roi_class = (const int*)d_in[7];
    const float* W_rpn_feat = (const float*)d_in[8];  const float* b_rpn_feat = (const float*)d_in[9];
    const float* W_rpn_del  = (const float*)d_in[10]; const float* b_rpn_del  = (const float*)d_in[11];
    const float* W_rpn_sc   = (const float*)d_in[12]; const float* b_rpn_sc   = (const float*)d_in[13];
    const float* W_roi_feat = (const float*)d_in[14]; const float* b_roi_feat = (const float*)d_in[15];
    const float* W_roi_del  = (const float*)d_in[16]; const float* b_roi_del  = (const float*)d_in[17];
    const float* W_roi_sc   = (const float*)d_in[18]; const float* b_roi_sc   = (const float*)d_in[19];
    const float* rpn_cls_W1  = (const float*)d_in[20]; const float* rpn_cls_b1  = (const float*)d_in[21];
    const float* rpn_cls_W2  = (const float*)d_in[22]; const float* rpn_cls_b2  = (const float*)d_in[23];
    const float* rpn_bbox_W1 = (const float*)d_in[24]; const float* rpn_bbox_b1 = (const float*)d_in[25];
    const float* rpn_bbox_W2 = (const float*)d_in[26]; const float* rpn_bbox_b2 = (const float*)d_in[27];
    const float* roi_cls_W1  = (const float*)d_in[28]; const float* roi_cls_b1  = (const float*)d_in[29];
    const float* roi_cls_W2  = (const float*)d_in[30]; const float* roi_cls_b2  = (const float*)d_in[31];
    const int* iter_ptr = (const int*)d_in[32];
    float* out = (float*)d_out;
    char*  wsb = (char*)d_ws;

    // ---- workspace layout ----
    unsigned short* roi_feat_sw = (unsigned short*)(wsb + 0);          // 4096x1024
    unsigned short* Ab_all      = (unsigned short*)(wsb + 0);          // launch 4+
    unsigned short* WfT_roi_c   = (unsigned short*)(wsb + 8388608);    // 1024x1024 (dead after comp)
    unsigned short* WfT_roi_b   = (unsigned short*)(wsb + 10485760);   // 1024x1024
    float*          part        = (float*)(wsb + 8388608);             // launch 5+
    unsigned short* comp_roi_c  = (unsigned short*)(wsb + 12582912);   // 256x1024
    unsigned short* comp_roi_b  = (unsigned short*)(wsb + 13107200);   // 256x1024
    unsigned short* comp_rpn_c  = (unsigned short*)(wsb + 13631488);   // 128x256
    unsigned short* comp_rpn_b  = (unsigned short*)(wsb + 13697024);   // 128x256
    float*          ext         = (float*)(wsb + 13762560);            // 4x1536 f32
    float*          zerobuf     = (float*)(wsb + 13787136);            // 1024 f32
    unsigned short* WfT_rpn_c   = (unsigned short*)(wsb + 13791232);   // 256x256
    unsigned short* WfT_rpn_b   = (unsigned short*)(wsb + 13922304);   // 256x256
    unsigned short* roi_W1_sw   = (unsigned short*)(wsb + 29360128);   // 256x1024
    unsigned short* h_roi_c     = (unsigned short*)(wsb + 29884416);   // 4096x256 linear
    unsigned short* h_roi_b     = (unsigned short*)(wsb + 31981568);   // 4096x256 linear
    unsigned short* rpn_feat_sw = (unsigned short*)(wsb + 34078720);   // 4096x256
    unsigned short* rpn_cW1_sw  = (unsigned short*)(wsb + 40632320);   // 128x256 padded
    unsigned short* rpn_bW1_sw  = (unsigned short*)(wsb + 40697856);   // 128x256 padded
    unsigned short* h_rpn_c     = (unsigned short*)(wsb + 40763392);   // 4096x128 linear
    unsigned short* h_rpn_b     = (unsigned short*)(wsb + 41811968);   // 4096x128 linear
    float* A_rpn_c = (float*)(wsb + 42861568);
    float* A_rpn_b = (float*)(wsb + 42992640);
    float* A_roi_c = (float*)(wsb + 43123712);
    float* A_roi_b = (float*)(wsb + 43254784);
    unsigned short* Db_roi = (unsigned short*)(wsb + 43385856);
    unsigned short* Db_rpn = (unsigned short*)(wsb + 43648000);
    float* part2 = (float*)(wsb + 43910144);                           // 32x192 f32

    // ---- 1: prep ----
    prep_kernel<<<dim3(3553), 256, 0, stream>>>(
        roi_feat, W_roi_feat, roi_cls_W1, rpn_feat, W_rpn_feat,
        rpn_cls_W1, rpn_bbox_W1, rpn_cls_b1, rpn_bbox_b1,
        roi_del, rpn_del,
        W_roi_del, W_roi_sc, b_roi_feat, b_roi_del, b_roi_sc, roi_cls_b1,
        W_rpn_del, W_rpn_sc, b_rpn_feat, b_rpn_del, b_rpn_sc,
        roi_feat_sw, WfT_roi_c, WfT_roi_b, roi_W1_sw, rpn_feat_sw,
        WfT_rpn_c, WfT_rpn_b, rpn_cW1_sw, rpn_bW1_sw,
        Db_roi, Db_rpn, ext, zerobuf, out);

    // ---- 2: composite weights comp = W1 @ Wf_half (144 wave-blocks) ----
    {
        GemmJobs js;
        js.n = 4;
        js.j[0] = { roi_W1_sw,  WfT_roi_c, comp_roi_c, zerobuf,
                    nullptr, nullptr, nullptr, nullptr, nullptr, nullptr,
                    8192, 32768, 16, 0, 1024, 16, 0 };
        // reference bug: roi bbox half also uses roi_cls_W1
        js.j[1] = { roi_W1_sw,  WfT_roi_b, comp_roi_b, zerobuf,
                    nullptr, nullptr, nullptr, nullptr, nullptr, nullptr,
                    8192, 32768, 16, 0, 1024, 16, 64 };
        js.j[2] = { rpn_cW1_sw, WfT_rpn_c, comp_rpn_c, zerobuf,
                    nullptr, nullptr, nullptr, nullptr, nullptr, nullptr,
                    4096, 8192, 8, 0, 256, 4, 128 };
        js.j[3] = { rpn_bW1_sw, WfT_rpn_b, comp_rpn_b, zerobuf,
                    nullptr, nullptr, nullptr, nullptr, nullptr, nullptr,
                    4096, 8192, 8, 0, 256, 4, 136 };
        gemm_reg<false, true, false><<<dim3(144), 64, 0, stream>>>(js);
    }

    // ---- 3: main GEMM h = relu(X@comp^T + extras) (768 wave-blocks) ----
    {
        GemmJobs js;
        js.n = 4;
        js.j[0] = { roi_feat_sw, comp_roi_c, h_roi_c, ext + 0 * 1536 + 1280,
                    roi_del, ext + 0 * 1536, zerobuf, roi_scale, ext + 0 * 1536 + 1024, zerobuf,
                    131072, 8192, 0, 256, 1024, 4, 0 };
        js.j[1] = { roi_feat_sw, comp_roi_b, h_roi_b, ext + 1 * 1536 + 1280,
                    roi_del, ext + 1 * 1536, zerobuf, roi_scale, ext + 1 * 1536 + 1024, zerobuf,
                    131072, 8192, 0, 256, 1024, 4, 256 };
        js.j[2] = { rpn_feat_sw, comp_rpn_c, h_rpn_c, ext + 2 * 1536 + 1280,
                    rpn_del, ext + 2 * 1536, zerobuf, rpn_scale, ext + 2 * 1536 + 1024, zerobuf,
                    131072, 4096, 0, 128, 256, 2, 512 };
        js.j[3] = { rpn_feat_sw, comp_rpn_b, h_rpn_b, ext + 3 * 1536 + 1280,
                    rpn_del, ext + 3 * 1536, zerobuf, rpn_scale, ext + 3 * 1536 + 1024, zerobuf,
                    131072, 4096, 0, 128, 256, 2, 640 };
        gemm_reg<true, false, true><<<dim3(768), 64, 0, stream>>>(js);
    }

    // ---- 4: all 4 alphas ----
    alphas_all<<<dim3(4096), 256, 0, stream>>>(
        h_rpn_c, h_rpn_b, h_roi_c, h_roi_b,
        rpn_cls_W2, rpn_bbox_W2, roi_cls_W2,
        rpn_cls_b2, rpn_bbox_b2, roi_cls_b2,
        iter_ptr, A_rpn_c, A_rpn_b, A_roi_c, A_roi_b, Ab_all);

    // ---- 5: loss pair-pass + means + class-sum partials ----
    finale_kernel<<<dim3(547), 256, 0, stream>>>(
        Ab_all, Db_roi, Db_rpn,
        A_roi_c, A_rpn_c, A_roi_b, A_rpn_b,
        roi_class, rpn_class, part, part2, out);

    // ---- 6: loss finish ----
    loss_finish_kernel<<<dim3(4), 256, 0, stream>>>(
        part, part2, A_roi_c, A_rpn_c, roi_class, rpn_class, out);
}